// Round 6
// baseline (611.500 us; speedup 1.0000x reference)
//
#include <hip/hip_runtime.h>
#include <math.h>

#define NN 100000
#define NE 3200000
#define NB 196          // dst-buckets of 512 nodes: 196*512 = 100352 >= NN
#define CAPB 20480      // bin entries per bucket (mean 16327, sigma~128 -> +32 sigma)
#define CAPE 20480      // csr entries per bucket (padded layout, no global scan)
#define EPB 8192        // edges per k_bin slab (512 threads, 16 edges/thread)

typedef _Float16 half4 __attribute__((ext_vector_type(4)));
typedef _Float16 half2v __attribute__((ext_vector_type(2)));

// g layout: two planes. plane0 = channels 0..15 (NN x 16 fp16), plane1 = 16..31.
// Within a plane, node row = 32 B; lane q in [0,8) owns channels {2q, 2q+1}.

// ---------------- binned CSR build ----------------

__global__ __launch_bounds__(512) void k_init_gcur(int* gcur) {
    int i = threadIdx.x;
    if (i < NB) gcur[i] = i * CAPB;
}

__global__ __launch_bounds__(512) void k_bin(const int* __restrict__ src,
                                             const int* __restrict__ dst,
                                             int* __restrict__ gcur,
                                             unsigned* __restrict__ bin) {
    __shared__ int hist[NB];
    __shared__ int base[NB];
    int tid = threadIdx.x;
    for (int i = tid; i < NB; i += 512) hist[i] = 0;
    __syncthreads();
    int e0 = blockIdx.x * EPB;
    int dcache[EPB / 512];
#pragma unroll
    for (int i = 0; i < EPB / 512; i++) {
        int e = e0 + i * 512 + tid;
        dcache[i] = (e < NE) ? dst[e] : -1;
        if (dcache[i] >= 0) atomicAdd(&hist[dcache[i] >> 9], 1);
    }
    __syncthreads();
    for (int i = tid; i < NB; i += 512) {
        int c = hist[i];
        base[i] = (c > 0) ? atomicAdd(&gcur[i], c) : 0;
    }
    __syncthreads();
    for (int i = tid; i < NB; i += 512) hist[i] = 0;
    __syncthreads();
#pragma unroll
    for (int i = 0; i < EPB / 512; i++) {
        int e = e0 + i * 512 + tid;
        int d = dcache[i];
        if (d >= 0) {
            int b = d >> 9;
            int pos = base[b] + atomicAdd(&hist[b], 1);
            bin[pos] = ((unsigned)src[e] << 9) | (unsigned)(d & 511);
        }
    }
}

__global__ __launch_bounds__(1024) void k_deg_off(const int* __restrict__ gcur,
                                                  const unsigned* __restrict__ bin,
                                                  int2* __restrict__ rc,
                                                  float* __restrict__ dis) {
    __shared__ int hist[512];
    __shared__ int sc[512];
    int b = blockIdx.x, tid = threadIdx.x;
    if (tid < 512) hist[tid] = 0;
    __syncthreads();
    int base = b * CAPB, cnt = gcur[b] - base;
    for (int i = tid; i < cnt; i += 1024) atomicAdd(&hist[bin[base + i] & 511], 1);
    __syncthreads();
    if (tid < 512) sc[tid] = hist[tid];
    __syncthreads();
    for (int off = 1; off < 512; off <<= 1) {
        int t = 0;
        if (tid < 512 && tid >= off) t = sc[tid - off];
        __syncthreads();
        if (tid < 512) sc[tid] += t;
        __syncthreads();
    }
    if (tid < 512) {
        int node = b * 512 + tid;
        if (node < NN) {
            int c = hist[tid];
            rc[node] = make_int2(b * CAPE + sc[tid] - c, c);
            dis[node] = rsqrtf((float)c + 1.0f);
        }
    }
}

__global__ __launch_bounds__(1024) void k_pass2(const int* __restrict__ gcur,
                                                const unsigned* __restrict__ bin,
                                                const int2* __restrict__ rc,
                                                const float* __restrict__ dis,
                                                int2* __restrict__ csr) {
    __shared__ int cur[512];
    __shared__ float sdis[512];
    int b = blockIdx.x, tid = threadIdx.x;
    if (tid < 512) {
        int node = b * 512 + tid;
        if (node < NN) {
            int2 r = rc[node];
            cur[tid] = r.x;
            sdis[tid] = rsqrtf((float)r.y + 1.0f);
        } else { cur[tid] = 0; sdis[tid] = 0.0f; }
    }
    __syncthreads();
    int base = b * CAPB, cnt = gcur[b] - base;
    for (int i = tid; i < cnt; i += 1024) {
        unsigned u = bin[base + i];
        int dl = u & 511;
        int s  = (int)(u >> 9);
        int pos = atomicAdd(&cur[dl], 1);
        float w = dis[s] * sdis[dl];
        csr[pos] = make_int2(s, __float_as_int(w));
    }
}

// ---------------- fused preproc (+ first GCN transform) ----------------
__global__ __launch_bounds__(256) void k_preproc(
        const float* __restrict__ x,
        const float* __restrict__ W_pre, const float* __restrict__ b_pre,
        const float* __restrict__ W_fc1, const float* __restrict__ b_fc1,
        const float* __restrict__ W_fc2, const float* __restrict__ b_fc2,
        const float* __restrict__ W_gcn,
        half4* __restrict__ ni, _Float16* __restrict__ g_out) {
    __shared__ __align__(16) float sWp[60];
    __shared__ __align__(16) float sbp[12];
    __shared__ __align__(16) float sW1[320];
    __shared__ __align__(16) float sb1[32];
    __shared__ __align__(16) float sW2[320];
    __shared__ __align__(16) float sb2[32];
    __shared__ __align__(16) float sWg[1024];
    __shared__ __align__(16) float s_h[32 * 36];
    int tid = threadIdx.x;
    if (tid < 60) sWp[tid] = W_pre[tid];
    if (tid >= 64 && tid < 74) sbp[tid - 64] = b_pre[tid - 64];
    for (int i = tid; i < 320; i += 256) { sW1[i] = W_fc1[i]; sW2[i] = W_fc2[i]; }
    if (tid >= 96 && tid < 128) sb1[tid - 96] = b_fc1[tid - 96];
    if (tid >= 128 && tid < 160) sb2[tid - 128] = b_fc2[tid - 128];
    for (int i = tid; i < 1024; i += 256) sWg[i] = W_gcn[i];
    __syncthreads();

    int ln = tid >> 3, q = tid & 7;
    int n = blockIdx.x * 32 + ln;

    float xv[6];
#pragma unroll
    for (int k = 0; k < 6; k++) xv[k] = x[n * 6 + k];
    float p[10];
#pragma unroll
    for (int j = 0; j < 10; j++) {
        float a = sbp[j];
#pragma unroll
        for (int k = 0; k < 6; k++) a = fmaf(xv[k], sWp[k * 10 + j], a);
        p[j] = 1.0f / (1.0f + expf(-a));
    }
    float4 a1 = ((const float4*)sb1)[q];
    float4 a2 = ((const float4*)sb2)[q];
#pragma unroll
    for (int k = 0; k < 10; k++) {
        float4 w1 = ((const float4*)sW1)[k * 8 + q];
        float4 w2 = ((const float4*)sW2)[k * 8 + q];
        a1.x = fmaf(p[k], w1.x, a1.x); a1.y = fmaf(p[k], w1.y, a1.y);
        a1.z = fmaf(p[k], w1.z, a1.z); a1.w = fmaf(p[k], w1.w, a1.w);
        a2.x = fmaf(p[k], w2.x, a2.x); a2.y = fmaf(p[k], w2.y, a2.y);
        a2.z = fmaf(p[k], w2.z, a2.z); a2.w = fmaf(p[k], w2.w, a2.w);
    }
    half4 niv;
    niv.x = (_Float16)fmaxf(a1.x, 0.f); niv.y = (_Float16)fmaxf(a1.y, 0.f);
    niv.z = (_Float16)fmaxf(a1.z, 0.f); niv.w = (_Float16)fmaxf(a1.w, 0.f);
    ni[n * 8 + q] = niv;
    float4 hv;
    hv.x = fmaxf(a2.x, 0.f); hv.y = fmaxf(a2.y, 0.f);
    hv.z = fmaxf(a2.z, 0.f); hv.w = fmaxf(a2.w, 0.f);
    *(float4*)&s_h[ln * 36 + 4 * q] = hv;
    __syncthreads();
    float4 o = make_float4(0.f, 0.f, 0.f, 0.f);
#pragma unroll
    for (int k = 0; k < 32; k++) {
        float v = s_h[ln * 36 + k];
        float4 wv = ((const float4*)sWg)[k * 8 + q];
        o.x = fmaf(v, wv.x, o.x); o.y = fmaf(v, wv.y, o.y);
        o.z = fmaf(v, wv.z, o.z); o.w = fmaf(v, wv.w, o.w);
    }
    half4 oh;
    oh.x = (_Float16)o.x; oh.y = (_Float16)o.y;
    oh.z = (_Float16)o.z; oh.w = (_Float16)o.w;
    // plane write: q<4 -> plane0 (ch 4q..4q+3), q>=4 -> plane1
    half4* op = (half4*)g_out;
    int plane = q >> 2, qq = q & 3;
    __builtin_nontemporal_store(oh, &op[(size_t)plane * (NN * 4) + n * 4 + qq]);
}

// ---------------- fused layer: two-phase gather + dense (+ transform | head) ----------------
template <bool LAST>
__global__ __launch_bounds__(256, 8) void k_layer(
        const _Float16* __restrict__ g_in,     // 2 planes of NN*16 fp16
        const int2* __restrict__ csr,
        const int2* __restrict__ rc,
        const half4* __restrict__ ni,
        const float* __restrict__ W_dense, const float* __restrict__ b_dense,
        const float* __restrict__ b_gcn,
        const float* __restrict__ W2,          // LAST ? W_f1 : W_gcn
        const float* __restrict__ b_f1,
        const float* __restrict__ W_f2, const float* __restrict__ b_f2,
        void* __restrict__ out)                // LAST ? float logits : planes g_out
{
    __shared__ __align__(16) float sWd[2048];
    __shared__ __align__(16) float sW2[LAST ? 2048 : 1024];
    __shared__ __align__(16) float sbd[32];
    __shared__ __align__(16) float sbg[32];
    __shared__ __align__(16) float sbf1[LAST ? 32 : 4];
    __shared__ __align__(16) float sWf2[LAST ? 64 : 4];
    __shared__ __align__(16) float sbf2[2];
    __shared__ __align__(16) _Float16 s_ni[32 * 36];
    __shared__ __align__(16) float s_t[32 * 36];

    int tid = threadIdx.x;
    for (int i = tid; i < 2048; i += 256) sWd[i] = W_dense[i];
    const int n2 = LAST ? 2048 : 1024;
    for (int i = tid; i < n2; i += 256) sW2[i] = W2[i];
    if (tid < 32) { sbd[tid] = b_dense[tid]; sbg[tid] = b_gcn[tid]; }
    if constexpr (LAST) {
        if (tid >= 64 && tid < 96) sbf1[tid - 64] = b_f1[tid - 64];
        if (tid >= 96 && tid < 160) sWf2[tid - 96] = W_f2[tid - 96];
        if (tid >= 160 && tid < 162) sbf2[tid - 160] = b_f2[tid - 160];
    }
    __syncthreads();

    int ln = tid >> 3, q = tid & 7;
    int n = blockIdx.x * 32 + ln;

    int2 r = rc[n];
    int start = r.x, cnt = r.y;
    float sn = 1.0f / ((float)cnt + 1.0f);
    const half2v* gp0 = (const half2v*)g_in;                       // idx n*8+q
    const half2v* gp1 = (const half2v*)(g_in + (size_t)NN * 16);
    const long long* csr8 = (const long long*)csr;
    int nbat = (cnt + 7) >> 3;

    // ---- phase A: channels 2q, 2q+1 (plane0 only; working set 3.2 MB) ----
    float a0, a1;
    {
        half2v s0 = gp0[n * 8 + q];
        a0 = (float)s0.x * sn; a1 = (float)s0.y * sn;
    }
    for (int b = 0; b < nbat; b += 2) {
        int i0 = b * 8 + q, i1 = i0 + 8;
        long long e0 = 0, e1 = 0;
        if (i0 < cnt) e0 = __builtin_nontemporal_load(csr8 + start + i0);
        if (i1 < cnt) e1 = __builtin_nontemporal_load(csr8 + start + i1);
#pragma unroll
        for (int j = 0; j < 8; j++) {
            int   s = __shfl((int)e0, j, 8);
            float w = __int_as_float(__shfl((int)((unsigned long long)e0 >> 32), j, 8));
            half2v gv = gp0[s * 8 + q];
            a0 = fmaf((float)gv.x, w, a0); a1 = fmaf((float)gv.y, w, a1);
        }
        if (b + 1 < nbat) {
#pragma unroll
            for (int j = 0; j < 8; j++) {
                int   s = __shfl((int)e1, j, 8);
                float w = __int_as_float(__shfl((int)((unsigned long long)e1 >> 32), j, 8));
                half2v gv = gp0[s * 8 + q];
                a0 = fmaf((float)gv.x, w, a0); a1 = fmaf((float)gv.y, w, a1);
            }
        }
    }
    {
        float2 tA;
        tA.x = fmaxf(a0 + sbg[2 * q + 0], 0.f);
        tA.y = fmaxf(a1 + sbg[2 * q + 1], 0.f);
        *(float2*)&s_t[ln * 36 + 2 * q] = tA;
    }
    __syncthreads();   // phase barrier: whole block leaves plane0 together

    // ---- phase B: channels 16+2q, 17+2q (plane1 only) ----
    float a2, a3;
    {
        half2v s1 = gp1[n * 8 + q];
        a2 = (float)s1.x * sn; a3 = (float)s1.y * sn;
    }
    for (int b = 0; b < nbat; b += 2) {
        int i0 = b * 8 + q, i1 = i0 + 8;
        long long e0 = 0, e1 = 0;
        if (i0 < cnt) e0 = __builtin_nontemporal_load(csr8 + start + i0);
        if (i1 < cnt) e1 = __builtin_nontemporal_load(csr8 + start + i1);
#pragma unroll
        for (int j = 0; j < 8; j++) {
            int   s = __shfl((int)e0, j, 8);
            float w = __int_as_float(__shfl((int)((unsigned long long)e0 >> 32), j, 8));
            half2v gv = gp1[s * 8 + q];
            a2 = fmaf((float)gv.x, w, a2); a3 = fmaf((float)gv.y, w, a3);
        }
        if (b + 1 < nbat) {
#pragma unroll
            for (int j = 0; j < 8; j++) {
                int   s = __shfl((int)e1, j, 8);
                float w = __int_as_float(__shfl((int)((unsigned long long)e1 >> 32), j, 8));
                half2v gv = gp1[s * 8 + q];
                a2 = fmaf((float)gv.x, w, a2); a3 = fmaf((float)gv.y, w, a3);
            }
        }
    }
    {
        float2 tB;
        tB.x = fmaxf(a2 + sbg[16 + 2 * q], 0.f);
        tB.y = fmaxf(a3 + sbg[17 + 2 * q], 0.f);
        *(float2*)&s_t[ln * 36 + 16 + 2 * q] = tB;
    }
    *(half4*)&s_ni[ln * 36 + 4 * q] = __builtin_nontemporal_load(&ni[n * 8 + q]);
    __syncthreads();

    // ---- dense: h = relu(concat(ni, t) @ W_dense + b_dense) ----
    float4 a = ((const float4*)sbd)[q];
#pragma unroll
    for (int k = 0; k < 32; k++) {
        float v = (float)s_ni[ln * 36 + k];
        float4 wv = ((const float4*)sWd)[k * 8 + q];
        a.x = fmaf(v, wv.x, a.x); a.y = fmaf(v, wv.y, a.y);
        a.z = fmaf(v, wv.z, a.z); a.w = fmaf(v, wv.w, a.w);
    }
#pragma unroll
    for (int k = 0; k < 32; k++) {
        float v = s_t[ln * 36 + k];
        float4 wv = ((const float4*)sWd)[(32 + k) * 8 + q];
        a.x = fmaf(v, wv.x, a.x); a.y = fmaf(v, wv.y, a.y);
        a.z = fmaf(v, wv.z, a.z); a.w = fmaf(v, wv.w, a.w);
    }
    float4 h;
    h.x = fmaxf(a.x, 0.f); h.y = fmaxf(a.y, 0.f);
    h.z = fmaxf(a.z, 0.f); h.w = fmaxf(a.w, 0.f);
    __syncthreads();
    *(float4*)&s_t[ln * 36 + 4 * q] = h;
    __syncthreads();

    if constexpr (!LAST) {
        float4 o = make_float4(0.f, 0.f, 0.f, 0.f);
#pragma unroll
        for (int k = 0; k < 32; k++) {
            float v = s_t[ln * 36 + k];
            float4 wv = ((const float4*)sW2)[k * 8 + q];
            o.x = fmaf(v, wv.x, o.x); o.y = fmaf(v, wv.y, o.y);
            o.z = fmaf(v, wv.z, o.z); o.w = fmaf(v, wv.w, o.w);
        }
        half4 oh;
        oh.x = (_Float16)o.x; oh.y = (_Float16)o.y;
        oh.z = (_Float16)o.z; oh.w = (_Float16)o.w;
        half4* op = (half4*)out;
        int plane = q >> 2, qq = q & 3;
        __builtin_nontemporal_store(oh, &op[(size_t)plane * (NN * 4) + n * 4 + qq]);
    } else {
        float4 a2v = ((const float4*)sbf1)[q];
#pragma unroll
        for (int k = 0; k < 32; k++) {
            float v = (float)s_ni[ln * 36 + k];
            float4 wv = ((const float4*)sW2)[k * 8 + q];
            a2v.x = fmaf(v, wv.x, a2v.x); a2v.y = fmaf(v, wv.y, a2v.y);
            a2v.z = fmaf(v, wv.z, a2v.z); a2v.w = fmaf(v, wv.w, a2v.w);
        }
#pragma unroll
        for (int k = 0; k < 32; k++) {
            float v = s_t[ln * 36 + k];
            float4 wv = ((const float4*)sW2)[(32 + k) * 8 + q];
            a2v.x = fmaf(v, wv.x, a2v.x); a2v.y = fmaf(v, wv.y, a2v.y);
            a2v.z = fmaf(v, wv.z, a2v.z); a2v.w = fmaf(v, wv.w, a2v.w);
        }
        float4 u;
        u.x = fmaxf(a2v.x, 0.f); u.y = fmaxf(a2v.y, 0.f);
        u.z = fmaxf(a2v.z, 0.f); u.w = fmaxf(a2v.w, 0.f);
        float p0 = u.x * sWf2[(4 * q + 0) * 2 + 0] + u.y * sWf2[(4 * q + 1) * 2 + 0]
                 + u.z * sWf2[(4 * q + 2) * 2 + 0] + u.w * sWf2[(4 * q + 3) * 2 + 0];
        float p1 = u.x * sWf2[(4 * q + 0) * 2 + 1] + u.y * sWf2[(4 * q + 1) * 2 + 1]
                 + u.z * sWf2[(4 * q + 2) * 2 + 1] + u.w * sWf2[(4 * q + 3) * 2 + 1];
        p0 += __shfl_down(p0, 4, 8); p1 += __shfl_down(p1, 4, 8);
        p0 += __shfl_down(p0, 2, 8); p1 += __shfl_down(p1, 2, 8);
        p0 += __shfl_down(p0, 1, 8); p1 += __shfl_down(p1, 1, 8);
        if (q == 0) {
            ((float*)out)[n * 2 + 0] = p0 + sbf2[0];
            ((float*)out)[n * 2 + 1] = p1 + sbf2[1];
        }
    }
}

// ---------------- launch ----------------

extern "C" void kernel_launch(void* const* d_in, const int* in_sizes, int n_in,
                              void* d_out, int out_size, void* d_ws, size_t ws_size,
                              hipStream_t stream) {
    const float* x      = (const float*)d_in[0];
    const int*   ei     = (const int*)d_in[1];
    const float* W_pre  = (const float*)d_in[2];
    const float* b_pre  = (const float*)d_in[3];
    const float* W_fc1  = (const float*)d_in[4];
    const float* b_fc1  = (const float*)d_in[5];
    const float* W_fc2  = (const float*)d_in[6];
    const float* b_fc2  = (const float*)d_in[7];
    const float* W_gcn  = (const float*)d_in[8];
    const float* b_gcn  = (const float*)d_in[9];
    const float* W_dense= (const float*)d_in[10];
    const float* b_dense= (const float*)d_in[11];
    const float* W_f1   = (const float*)d_in[12];
    const float* b_f1   = (const float*)d_in[13];
    const float* W_f2   = (const float*)d_in[14];
    const float* b_f2   = (const float*)d_in[15];

    const int* src = ei;
    const int* dst = ei + NE;

    size_t off = 0;
    auto alloc = [&](size_t bytes) -> void* {
        off = (off + 255) & ~(size_t)255;
        void* p = (char*)d_ws + off;
        off += bytes;
        return p;
    };
    int2*  rc      = (int2*) alloc((size_t)NN * sizeof(int2));
    float* dis     = (float*)alloc(NN * sizeof(float));
    int*   gcur    = (int*)  alloc(NB * sizeof(int));
    int2*  csr     = (int2*) alloc((size_t)NB * CAPE * sizeof(int2));   // 32.1 MB padded
    // bin (16.1 MB) overlays gA+gB (2 x 6.4 MB fp16): bin dead before preproc.
    char*  Ureg    = (char*) alloc((size_t)NB * CAPB * sizeof(unsigned));
    half4* ni      = (half4*)alloc((size_t)NN * 32 * sizeof(_Float16));
    unsigned* bin  = (unsigned*)Ureg;
    _Float16* gA   = (_Float16*)Ureg;
    _Float16* gB   = (_Float16*)(Ureg + (size_t)NN * 32 * sizeof(_Float16));

    const int binBlocks   = (NE + EPB - 1) / EPB; // 391
    const int fusedBlocks = NN / 32;              // 3125

    k_init_gcur<<<1, 512, 0, stream>>>(gcur);
    k_bin<<<binBlocks, 512, 0, stream>>>(src, dst, gcur, bin);
    k_deg_off<<<NB, 1024, 0, stream>>>(gcur, bin, rc, dis);
    k_pass2<<<NB, 1024, 0, stream>>>(gcur, bin, rc, dis, csr);

    k_preproc<<<fusedBlocks, 256, 0, stream>>>(x, W_pre, b_pre, W_fc1, b_fc1,
                                               W_fc2, b_fc2, W_gcn, ni, gA);

    _Float16* gin = gA;
    _Float16* gout = gB;
    for (int l = 0; l < 5; l++) {
        k_layer<false><<<fusedBlocks, 256, 0, stream>>>(
            gin, csr, rc, ni, W_dense, b_dense, b_gcn,
            W_gcn, nullptr, nullptr, nullptr, (void*)gout);
        _Float16* tmp = gin; gin = gout; gout = tmp;
    }
    k_layer<true><<<fusedBlocks, 256, 0, stream>>>(
        gin, csr, rc, ni, W_dense, b_dense, b_gcn,
        W_f1, b_f1, W_f2, b_f2, d_out);
}

// Round 7
// 454.046 us; speedup vs baseline: 1.3468x; 1.3468x over previous
//
#include <hip/hip_runtime.h>
#include <math.h>

#define NN 100000
#define NE 3200000
#define NB 196          // dst-buckets of 512 nodes: 196*512 = 100352 >= NN
#define CAPB 20480      // bin entries per bucket (mean 16384, +~32 sigma)
#define CAPE 36864      // csr entries per bucket (rows padded to x32: max ~32256)
#define EPB 8192        // edges per k_bin slab (512 threads, 16 edges/thread)

typedef _Float16 half4 __attribute__((ext_vector_type(4)));

// g' = dis[n] * (h @ W_gcn), fp16, row = 64 B, plus zero sentinel row NN.
// csr holds src indices only (4 B); rows padded to x32 with sentinel NN.

// ---------------- binned CSR build ----------------

__global__ __launch_bounds__(512) void k_init_gcur(int* gcur) {
    int i = threadIdx.x;
    if (i < NB) gcur[i] = i * CAPB;
}

__global__ __launch_bounds__(512) void k_bin(const int* __restrict__ src,
                                             const int* __restrict__ dst,
                                             int* __restrict__ gcur,
                                             unsigned* __restrict__ bin) {
    __shared__ int hist[NB];
    __shared__ int base[NB];
    int tid = threadIdx.x;
    for (int i = tid; i < NB; i += 512) hist[i] = 0;
    __syncthreads();
    int e0 = blockIdx.x * EPB;
    int dcache[EPB / 512];
#pragma unroll
    for (int i = 0; i < EPB / 512; i++) {
        int e = e0 + i * 512 + tid;
        dcache[i] = (e < NE) ? dst[e] : -1;
        if (dcache[i] >= 0) atomicAdd(&hist[dcache[i] >> 9], 1);
    }
    __syncthreads();
    for (int i = tid; i < NB; i += 512) {
        int c = hist[i];
        base[i] = (c > 0) ? atomicAdd(&gcur[i], c) : 0;
    }
    __syncthreads();
    for (int i = tid; i < NB; i += 512) hist[i] = 0;
    __syncthreads();
#pragma unroll
    for (int i = 0; i < EPB / 512; i++) {
        int e = e0 + i * 512 + tid;
        int d = dcache[i];
        if (d >= 0) {
            int b = d >> 9;
            int pos = base[b] + atomicAdd(&hist[b], 1);
            bin[pos] = ((unsigned)src[e] << 9) | (unsigned)(d & 511);
        }
    }
}

// Per-bucket histogram -> scan of x32-padded sizes -> rc=(padded start, cnt), dis.
__global__ __launch_bounds__(1024) void k_deg_off(const int* __restrict__ gcur,
                                                  const unsigned* __restrict__ bin,
                                                  int2* __restrict__ rc,
                                                  float* __restrict__ dis) {
    __shared__ int hist[512];
    __shared__ int sc[512];
    int b = blockIdx.x, tid = threadIdx.x;
    if (tid < 512) hist[tid] = 0;
    __syncthreads();
    int base = b * CAPB, cnt = gcur[b] - base;
    for (int i = tid; i < cnt; i += 1024) atomicAdd(&hist[bin[base + i] & 511], 1);
    __syncthreads();
    int r32 = 0;
    if (tid < 512) { r32 = (hist[tid] + 31) & ~31; sc[tid] = r32; }
    __syncthreads();
    for (int off = 1; off < 512; off <<= 1) {
        int t = 0;
        if (tid < 512 && tid >= off) t = sc[tid - off];
        __syncthreads();
        if (tid < 512) sc[tid] += t;
        __syncthreads();
    }
    if (tid < 512) {
        int node = b * 512 + tid;
        if (node < NN) {
            int c = hist[tid];
            rc[node] = make_int2(b * CAPE + sc[tid] - r32, c);
            dis[node] = rsqrtf((float)c + 1.0f);
        }
    }
}

// Scatter src-only entries; pad each row to x32 with sentinel NN.
__global__ __launch_bounds__(1024) void k_pass2(const int* __restrict__ gcur,
                                                const unsigned* __restrict__ bin,
                                                const int2* __restrict__ rc,
                                                int* __restrict__ csr) {
    __shared__ int cur[512];
    __shared__ int rend[512];
    int b = blockIdx.x, tid = threadIdx.x;
    if (tid < 512) {
        int node = b * 512 + tid;
        if (node < NN) {
            int2 r = rc[node];
            cur[tid] = r.x;
            rend[tid] = r.x + ((r.y + 31) & ~31);
        } else { cur[tid] = 0; rend[tid] = 0; }
    }
    __syncthreads();
    int base = b * CAPB, cnt = gcur[b] - base;
    for (int i = tid; i < cnt; i += 1024) {
        unsigned u = bin[base + i];
        int dl = u & 511;
        int pos = atomicAdd(&cur[dl], 1);
        csr[pos] = (int)(u >> 9);
    }
    __syncthreads();
    if (tid < 512) {
        for (int i = cur[tid]; i < rend[tid]; i++) csr[i] = NN;
    }
}

// ---------------- fused preproc (+ first GCN transform, pre-scaled) ----------------
__global__ __launch_bounds__(256) void k_preproc(
        const float* __restrict__ x,
        const float* __restrict__ W_pre, const float* __restrict__ b_pre,
        const float* __restrict__ W_fc1, const float* __restrict__ b_fc1,
        const float* __restrict__ W_fc2, const float* __restrict__ b_fc2,
        const float* __restrict__ W_gcn, const float* __restrict__ dis,
        half4* __restrict__ ni, half4* __restrict__ g_out) {
    __shared__ __align__(16) float sWp[60];
    __shared__ __align__(16) float sbp[12];
    __shared__ __align__(16) float sW1[320];
    __shared__ __align__(16) float sb1[32];
    __shared__ __align__(16) float sW2[320];
    __shared__ __align__(16) float sb2[32];
    __shared__ __align__(16) float sWg[1024];
    __shared__ __align__(16) float s_h[32 * 36];
    int tid = threadIdx.x;
    if (tid < 60) sWp[tid] = W_pre[tid];
    if (tid >= 64 && tid < 74) sbp[tid - 64] = b_pre[tid - 64];
    for (int i = tid; i < 320; i += 256) { sW1[i] = W_fc1[i]; sW2[i] = W_fc2[i]; }
    if (tid >= 96 && tid < 128) sb1[tid - 96] = b_fc1[tid - 96];
    if (tid >= 128 && tid < 160) sb2[tid - 128] = b_fc2[tid - 128];
    for (int i = tid; i < 1024; i += 256) sWg[i] = W_gcn[i];
    __syncthreads();

    int ln = tid >> 3, q = tid & 7;
    int n = blockIdx.x * 32 + ln;

    float xv[6];
#pragma unroll
    for (int k = 0; k < 6; k++) xv[k] = x[n * 6 + k];
    float p[10];
#pragma unroll
    for (int j = 0; j < 10; j++) {
        float a = sbp[j];
#pragma unroll
        for (int k = 0; k < 6; k++) a = fmaf(xv[k], sWp[k * 10 + j], a);
        p[j] = 1.0f / (1.0f + expf(-a));
    }
    float4 a1 = ((const float4*)sb1)[q];
    float4 a2 = ((const float4*)sb2)[q];
#pragma unroll
    for (int k = 0; k < 10; k++) {
        float4 w1 = ((const float4*)sW1)[k * 8 + q];
        float4 w2 = ((const float4*)sW2)[k * 8 + q];
        a1.x = fmaf(p[k], w1.x, a1.x); a1.y = fmaf(p[k], w1.y, a1.y);
        a1.z = fmaf(p[k], w1.z, a1.z); a1.w = fmaf(p[k], w1.w, a1.w);
        a2.x = fmaf(p[k], w2.x, a2.x); a2.y = fmaf(p[k], w2.y, a2.y);
        a2.z = fmaf(p[k], w2.z, a2.z); a2.w = fmaf(p[k], w2.w, a2.w);
    }
    half4 niv;
    niv.x = (_Float16)fmaxf(a1.x, 0.f); niv.y = (_Float16)fmaxf(a1.y, 0.f);
    niv.z = (_Float16)fmaxf(a1.z, 0.f); niv.w = (_Float16)fmaxf(a1.w, 0.f);
    ni[n * 8 + q] = niv;
    float4 hv;
    hv.x = fmaxf(a2.x, 0.f); hv.y = fmaxf(a2.y, 0.f);
    hv.z = fmaxf(a2.z, 0.f); hv.w = fmaxf(a2.w, 0.f);
    *(float4*)&s_h[ln * 36 + 4 * q] = hv;
    __syncthreads();
    float4 o = make_float4(0.f, 0.f, 0.f, 0.f);
#pragma unroll
    for (int k = 0; k < 32; k++) {
        float v = s_h[ln * 36 + k];
        float4 wv = ((const float4*)sWg)[k * 8 + q];
        o.x = fmaf(v, wv.x, o.x); o.y = fmaf(v, wv.y, o.y);
        o.z = fmaf(v, wv.z, o.z); o.w = fmaf(v, wv.w, o.w);
    }
    float dn = dis[n];
    half4 oh;
    oh.x = (_Float16)(o.x * dn); oh.y = (_Float16)(o.y * dn);
    oh.z = (_Float16)(o.z * dn); oh.w = (_Float16)(o.w * dn);
    g_out[n * 8 + q] = oh;
    if (blockIdx.x == 0 && tid < 8) {
        half4 z = (half4)(_Float16)0.f;
        g_out[NN * 8 + tid] = z;     // zero sentinel row
    }
}

// ---------------- fused layer ----------------
template <bool LAST>
__global__ __launch_bounds__(256, 8) void k_layer(
        const half4* __restrict__ g_in,        // (NN+1) rows of 64 B, pre-scaled
        const int* __restrict__ csr,           // src-only, rows padded to x32
        const int2* __restrict__ rc,
        const half4* __restrict__ ni,
        const float* __restrict__ W_dense, const float* __restrict__ b_dense,
        const float* __restrict__ b_gcn,
        const float* __restrict__ W2,          // LAST ? W_f1 : W_gcn
        const float* __restrict__ b_f1,
        const float* __restrict__ W_f2, const float* __restrict__ b_f2,
        void* __restrict__ out)                // LAST ? float logits : half4 g_out
{
    __shared__ __align__(16) float sWd[2048];
    __shared__ __align__(16) float sW2[LAST ? 2048 : 1024];
    __shared__ __align__(16) float sbd[32];
    __shared__ __align__(16) float sbg[32];
    __shared__ __align__(16) float sbf1[LAST ? 32 : 4];
    __shared__ __align__(16) float sWf2[LAST ? 64 : 4];
    __shared__ __align__(16) float sbf2[2];
    __shared__ __align__(16) _Float16 s_ni[32 * 36];
    __shared__ __align__(16) float s_t[32 * 36];

    int tid = threadIdx.x;
    for (int i = tid; i < 2048; i += 256) sWd[i] = W_dense[i];
    const int n2 = LAST ? 2048 : 1024;
    for (int i = tid; i < n2; i += 256) sW2[i] = W2[i];
    if (tid < 32) { sbd[tid] = b_dense[tid]; sbg[tid] = b_gcn[tid]; }
    if constexpr (LAST) {
        if (tid >= 64 && tid < 96) sbf1[tid - 64] = b_f1[tid - 64];
        if (tid >= 96 && tid < 160) sWf2[tid - 96] = W_f2[tid - 96];
        if (tid >= 160 && tid < 162) sbf2[tid - 160] = b_f2[tid - 160];
    }
    __syncthreads();

    int ln = tid >> 3, q = tid & 7;
    int n = blockIdx.x * 32 + ln;

    // ---- gather: acc = g'[n] + sum g'[src]; t = relu(dis_d*acc + b) ----
    int2 r = rc[n];
    int start = r.x, cnt = r.y;
    float disd = rsqrtf((float)cnt + 1.0f);
    float4 acc;
    {
        half4 gs = g_in[n * 8 + q];
        acc.x = (float)gs.x; acc.y = (float)gs.y;
        acc.z = (float)gs.z; acc.w = (float)gs.w;
    }
    int nb32 = (cnt + 31) >> 5;
    for (int b = 0; b < nb32; b++) {
        int p = start + b * 32 + q;
        int s0 = __builtin_nontemporal_load(csr + p);
        int s1 = __builtin_nontemporal_load(csr + p + 8);
        int s2 = __builtin_nontemporal_load(csr + p + 16);
        int s3 = __builtin_nontemporal_load(csr + p + 24);
#pragma unroll
        for (int j = 0; j < 8; j++) {
            int s = __shfl(s0, j, 8);
            half4 gv = g_in[s * 8 + q];
            acc.x += (float)gv.x; acc.y += (float)gv.y;
            acc.z += (float)gv.z; acc.w += (float)gv.w;
        }
#pragma unroll
        for (int j = 0; j < 8; j++) {
            int s = __shfl(s1, j, 8);
            half4 gv = g_in[s * 8 + q];
            acc.x += (float)gv.x; acc.y += (float)gv.y;
            acc.z += (float)gv.z; acc.w += (float)gv.w;
        }
#pragma unroll
        for (int j = 0; j < 8; j++) {
            int s = __shfl(s2, j, 8);
            half4 gv = g_in[s * 8 + q];
            acc.x += (float)gv.x; acc.y += (float)gv.y;
            acc.z += (float)gv.z; acc.w += (float)gv.w;
        }
#pragma unroll
        for (int j = 0; j < 8; j++) {
            int s = __shfl(s3, j, 8);
            half4 gv = g_in[s * 8 + q];
            acc.x += (float)gv.x; acc.y += (float)gv.y;
            acc.z += (float)gv.z; acc.w += (float)gv.w;
        }
    }
    float4 t;
    t.x = fmaxf(fmaf(disd, acc.x, sbg[4 * q + 0]), 0.f);
    t.y = fmaxf(fmaf(disd, acc.y, sbg[4 * q + 1]), 0.f);
    t.z = fmaxf(fmaf(disd, acc.z, sbg[4 * q + 2]), 0.f);
    t.w = fmaxf(fmaf(disd, acc.w, sbg[4 * q + 3]), 0.f);
    *(float4*)&s_t[ln * 36 + 4 * q] = t;
    *(half4*)&s_ni[ln * 36 + 4 * q] = __builtin_nontemporal_load(&ni[n * 8 + q]);
    __syncthreads();

    // ---- dense: h = relu(concat(ni, t) @ W_dense + b_dense) ----
    float4 a = ((const float4*)sbd)[q];
#pragma unroll
    for (int k = 0; k < 32; k++) {
        float v = (float)s_ni[ln * 36 + k];
        float4 wv = ((const float4*)sWd)[k * 8 + q];
        a.x = fmaf(v, wv.x, a.x); a.y = fmaf(v, wv.y, a.y);
        a.z = fmaf(v, wv.z, a.z); a.w = fmaf(v, wv.w, a.w);
    }
#pragma unroll
    for (int k = 0; k < 32; k++) {
        float v = s_t[ln * 36 + k];
        float4 wv = ((const float4*)sWd)[(32 + k) * 8 + q];
        a.x = fmaf(v, wv.x, a.x); a.y = fmaf(v, wv.y, a.y);
        a.z = fmaf(v, wv.z, a.z); a.w = fmaf(v, wv.w, a.w);
    }
    float4 h;
    h.x = fmaxf(a.x, 0.f); h.y = fmaxf(a.y, 0.f);
    h.z = fmaxf(a.z, 0.f); h.w = fmaxf(a.w, 0.f);
    __syncthreads();
    *(float4*)&s_t[ln * 36 + 4 * q] = h;
    __syncthreads();

    if constexpr (!LAST) {
        // ---- transform + pre-scale: g'_out = dis_d * (h @ W_gcn) ----
        float4 o = make_float4(0.f, 0.f, 0.f, 0.f);
#pragma unroll
        for (int k = 0; k < 32; k++) {
            float v = s_t[ln * 36 + k];
            float4 wv = ((const float4*)sW2)[k * 8 + q];
            o.x = fmaf(v, wv.x, o.x); o.y = fmaf(v, wv.y, o.y);
            o.z = fmaf(v, wv.z, o.z); o.w = fmaf(v, wv.w, o.w);
        }
        half4 oh;
        oh.x = (_Float16)(o.x * disd); oh.y = (_Float16)(o.y * disd);
        oh.z = (_Float16)(o.z * disd); oh.w = (_Float16)(o.w * disd);
        half4* op = (half4*)out;
        op[n * 8 + q] = oh;
        if (blockIdx.x == 0 && tid < 8) {
            half4 z = (half4)(_Float16)0.f;
            op[NN * 8 + tid] = z;
        }
    } else {
        float4 a2v = ((const float4*)sbf1)[q];
#pragma unroll
        for (int k = 0; k < 32; k++) {
            float v = (float)s_ni[ln * 36 + k];
            float4 wv = ((const float4*)sW2)[k * 8 + q];
            a2v.x = fmaf(v, wv.x, a2v.x); a2v.y = fmaf(v, wv.y, a2v.y);
            a2v.z = fmaf(v, wv.z, a2v.z); a2v.w = fmaf(v, wv.w, a2v.w);
        }
#pragma unroll
        for (int k = 0; k < 32; k++) {
            float v = s_t[ln * 36 + k];
            float4 wv = ((const float4*)sW2)[(32 + k) * 8 + q];
            a2v.x = fmaf(v, wv.x, a2v.x); a2v.y = fmaf(v, wv.y, a2v.y);
            a2v.z = fmaf(v, wv.z, a2v.z); a2v.w = fmaf(v, wv.w, a2v.w);
        }
        float4 u;
        u.x = fmaxf(a2v.x, 0.f); u.y = fmaxf(a2v.y, 0.f);
        u.z = fmaxf(a2v.z, 0.f); u.w = fmaxf(a2v.w, 0.f);
        float p0 = u.x * sWf2[(4 * q + 0) * 2 + 0] + u.y * sWf2[(4 * q + 1) * 2 + 0]
                 + u.z * sWf2[(4 * q + 2) * 2 + 0] + u.w * sWf2[(4 * q + 3) * 2 + 0];
        float p1 = u.x * sWf2[(4 * q + 0) * 2 + 1] + u.y * sWf2[(4 * q + 1) * 2 + 1]
                 + u.z * sWf2[(4 * q + 2) * 2 + 1] + u.w * sWf2[(4 * q + 3) * 2 + 1];
        p0 += __shfl_down(p0, 4, 8); p1 += __shfl_down(p1, 4, 8);
        p0 += __shfl_down(p0, 2, 8); p1 += __shfl_down(p1, 2, 8);
        p0 += __shfl_down(p0, 1, 8); p1 += __shfl_down(p1, 1, 8);
        if (q == 0) {
            ((float*)out)[n * 2 + 0] = p0 + sbf2[0];
            ((float*)out)[n * 2 + 1] = p1 + sbf2[1];
        }
    }
}

// ---------------- launch ----------------

extern "C" void kernel_launch(void* const* d_in, const int* in_sizes, int n_in,
                              void* d_out, int out_size, void* d_ws, size_t ws_size,
                              hipStream_t stream) {
    const float* x      = (const float*)d_in[0];
    const int*   ei     = (const int*)d_in[1];
    const float* W_pre  = (const float*)d_in[2];
    const float* b_pre  = (const float*)d_in[3];
    const float* W_fc1  = (const float*)d_in[4];
    const float* b_fc1  = (const float*)d_in[5];
    const float* W_fc2  = (const float*)d_in[6];
    const float* b_fc2  = (const float*)d_in[7];
    const float* W_gcn  = (const float*)d_in[8];
    const float* b_gcn  = (const float*)d_in[9];
    const float* W_dense= (const float*)d_in[10];
    const float* b_dense= (const float*)d_in[11];
    const float* W_f1   = (const float*)d_in[12];
    const float* b_f1   = (const float*)d_in[13];
    const float* W_f2   = (const float*)d_in[14];
    const float* b_f2   = (const float*)d_in[15];

    const int* src = ei;
    const int* dst = ei + NE;

    size_t off = 0;
    auto alloc = [&](size_t bytes) -> void* {
        off = (off + 255) & ~(size_t)255;
        void* p = (char*)d_ws + off;
        off += bytes;
        return p;
    };
    int2*  rc      = (int2*) alloc((size_t)NN * sizeof(int2));
    float* dis     = (float*)alloc(NN * sizeof(float));
    int*   gcur    = (int*)  alloc(NB * sizeof(int));
    int*   csr     = (int*)  alloc((size_t)NB * CAPE * sizeof(int));    // 28.9 MB padded
    // bin (16.05 MB) overlays gA+gB (2 x 6.4 MB fp16): bin dead before preproc.
    char*  Ureg    = (char*) alloc((size_t)NB * CAPB * sizeof(unsigned));
    half4* ni      = (half4*)alloc((size_t)NN * 32 * sizeof(_Float16));
    unsigned* bin  = (unsigned*)Ureg;
    half4* gA      = (half4*)Ureg;
    half4* gB      = (half4*)(Ureg + (size_t)(NN + 1) * 32 * sizeof(_Float16));

    const int binBlocks   = (NE + EPB - 1) / EPB; // 391
    const int fusedBlocks = NN / 32;              // 3125

    k_init_gcur<<<1, 512, 0, stream>>>(gcur);
    k_bin<<<binBlocks, 512, 0, stream>>>(src, dst, gcur, bin);
    k_deg_off<<<NB, 1024, 0, stream>>>(gcur, bin, rc, dis);
    k_pass2<<<NB, 1024, 0, stream>>>(gcur, bin, rc, csr);

    k_preproc<<<fusedBlocks, 256, 0, stream>>>(x, W_pre, b_pre, W_fc1, b_fc1,
                                               W_fc2, b_fc2, W_gcn, dis, ni, gA);

    half4* gin = gA;
    half4* gout = gB;
    for (int l = 0; l < 5; l++) {
        k_layer<false><<<fusedBlocks, 256, 0, stream>>>(
            gin, csr, rc, ni, W_dense, b_dense, b_gcn,
            W_gcn, nullptr, nullptr, nullptr, (void*)gout);
        half4* tmp = gin; gin = gout; gout = tmp;
    }
    k_layer<true><<<fusedBlocks, 256, 0, stream>>>(
        gin, csr, rc, ni, W_dense, b_dense, b_gcn,
        W_f1, b_f1, W_f2, b_f2, d_out);
}